// Round 1
// baseline (16674.678 us; speedup 1.0000x reference)
//
#include <hip/hip_runtime.h>
#include <math.h>

#define TT 36
#define NP 160
#define KDIM 641
#define PP 512
#define LDA 672          // padded row stride for A (mult of 16, covers k0+31+3)
#define LAM 0.1f
#define EPSW 0.01f
#define NITER 200
#define NPOW 1200

// ---------------- dictionary ----------------
__global__ void k_build_dic(const float* __restrict__ rr, const float* __restrict__ th,
                            float* __restrict__ D, float* __restrict__ outD) {
  int idx = blockIdx.x * blockDim.x + threadIdx.x;
  if (idx >= TT * KDIM) return;
  int t = idx / KDIM, k = idx % KDIM;
  float v;
  if (k == 0) {
    v = 1.0f;
  } else {
    int g = (k - 1) / NP;     // 0:p*cos 1:m*cos 2:p*sin 3:m*sin
    int p = (k - 1) % NP;
    float ft = (float)t;
    float pw = powf(rr[p], ft);
    if ((g == 1 || g == 3) && (t & 1)) pw = -pw;
    float ang = ft * th[p];
    v = pw * ((g < 2) ? cosf(ang) : sinf(ang));
  }
  D[idx] = v;
  outD[idx] = v;
}

// ---------------- G = D D^T (36x36) ----------------
__global__ void k_G(const float* __restrict__ D, float* __restrict__ G) {
  int idx = blockIdx.x * blockDim.x + threadIdx.x;
  if (idx >= TT * TT) return;
  int i = idx / TT, j = idx % TT;
  float s = 0.0f;
  for (int k = 0; k < KDIM; ++k) s = fmaf(D[i * KDIM + k], D[j * KDIM + k], s);
  G[idx] = s;
}

// ---------------- power iteration on 36x36 (one wave) ----------------
__global__ void k_power(const float* __restrict__ G, float* __restrict__ Lb) {
  int lane = threadIdx.x;   // blockDim = 64 (one wave)
  float g[TT];
#pragma unroll
  for (int j = 0; j < TT; ++j) g[j] = (lane < TT) ? G[lane * TT + j] : 0.0f;
  float v = (lane < TT) ? 1.0f : 0.0f;
  for (int it = 0; it < NPOW; ++it) {
    float u = 0.0f;
#pragma unroll
    for (int j = 0; j < TT; ++j) u = fmaf(g[j], __shfl(v, j, 64), u);
    float s = u * u;
#pragma unroll
    for (int o = 32; o >= 1; o >>= 1) s += __shfl_xor(s, o, 64);
    v = u * rsqrtf(s);
  }
  float u = 0.0f;
#pragma unroll
  for (int j = 0; j < TT; ++j) u = fmaf(g[j], __shfl(v, j, 64), u);
  float num = v * u, den = v * v;
#pragma unroll
  for (int o = 32; o >= 1; o >>= 1) {
    num += __shfl_xor(num, o, 64);
    den += __shfl_xor(den, o, 64);
  }
  if (lane == 0) {
    float L = num / den;   // Rayleigh quotient = lambda_max
    Lb[0] = L;
    Lb[1] = 1.0f / L;
  }
}

// ---------------- A = I - DtD * Linv (padded to LDA, pad = 0) ----------------
__global__ void k_A(const float* __restrict__ D, const float* __restrict__ Lb,
                    float* __restrict__ A) {
  int idx = blockIdx.x * blockDim.x + threadIdx.x;
  if (idx >= KDIM * LDA) return;
  int i = idx / LDA, j = idx % LDA;
  if (j >= KDIM) { A[idx] = 0.0f; return; }
  float s = 0.0f;
#pragma unroll 6
  for (int t = 0; t < TT; ++t) s = fmaf(D[t * KDIM + i], D[t * KDIM + j], s);
  A[idx] = ((i == j) ? 1.0f : 0.0f) - s * Lb[1];
}

// ---------------- c0 = DtY * Linv ----------------
__global__ void k_c0(const float* __restrict__ D, const float* __restrict__ X,
                     const float* __restrict__ Lb, float* __restrict__ c0) {
  int idx = blockIdx.x * blockDim.x + threadIdx.x;
  if (idx >= KDIM * PP) return;
  int k = idx / PP, p = idx % PP;
  float s = 0.0f;
#pragma unroll 6
  for (int t = 0; t < TT; ++t) s = fmaf(D[t * KDIM + k], X[t * PP + p], s);
  c0[idx] = s * Lb[1];
}

// ---------------- per-round: c± and zero-init x,y ----------------
__global__ void k_c(const float* __restrict__ c0, const float* __restrict__ w,
                    const float* __restrict__ Lb, float* __restrict__ cm,
                    float* __restrict__ cp, float* __restrict__ xa,
                    float* __restrict__ ya, int first) {
  int idx = blockIdx.x * blockDim.x + threadIdx.x;
  if (idx >= KDIM * PP) return;
  float scale = LAM * Lb[1];
  float wl = first ? scale : w[idx] * Lb[2] * scale;  // Lb[2] = 1/||wr||
  float c = c0[idx];
  cm[idx] = c - wl;
  cp[idx] = c + wl;
  xa[idx] = 0.0f;
  ya[idx] = 0.0f;
}

// ---------------- one FISTA iteration: x,y = update(A@y_in) ----------------
#define BM 32
#define BN 64
#define BK 32

__global__ __launch_bounds__(256) void k_fista(
    const float* __restrict__ A, const float* __restrict__ yin,
    const float* __restrict__ xin, const float* __restrict__ cm,
    const float* __restrict__ cp, float* __restrict__ xout,
    float* __restrict__ yout, float mu) {
  __shared__ float As[BK][BM + 2];
  __shared__ float Bs[BK][BN];
  const int tid = threadIdx.x;
  const int tx = tid & 15;
  const int ty = tid >> 4;
  const int row0 = blockIdx.y * BM;
  const int col0 = blockIdx.x * BN;

  float acc[2][4] = {{0.f, 0.f, 0.f, 0.f}, {0.f, 0.f, 0.f, 0.f}};

  const int am = tid >> 3;        // 0..31 (row within A tile)
  const int ak = (tid & 7) << 2;  // 0,4,...,28
  const int nb = (tid & 15) << 2; // 0..60
  const int kb = tid >> 4;        // 0..15

  for (int k0 = 0; k0 < KDIM; k0 += BK) {
    {
      int row = row0 + am;
      float4 v = make_float4(0.f, 0.f, 0.f, 0.f);
      if (row < KDIM) v = *reinterpret_cast<const float4*>(&A[row * LDA + k0 + ak]);
      As[ak + 0][am] = v.x;
      As[ak + 1][am] = v.y;
      As[ak + 2][am] = v.z;
      As[ak + 3][am] = v.w;
    }
#pragma unroll
    for (int h = 0; h < 2; ++h) {
      int k = k0 + kb + h * 16;
      float4 v = make_float4(0.f, 0.f, 0.f, 0.f);
      if (k < KDIM) v = *reinterpret_cast<const float4*>(&yin[k * PP + col0 + nb]);
      *reinterpret_cast<float4*>(&Bs[kb + h * 16][nb]) = v;
    }
    __syncthreads();
#pragma unroll
    for (int kk = 0; kk < BK; ++kk) {
      float2 a = *reinterpret_cast<const float2*>(&As[kk][ty * 2]);
      float4 b = *reinterpret_cast<const float4*>(&Bs[kk][tx * 4]);
      acc[0][0] = fmaf(a.x, b.x, acc[0][0]);
      acc[0][1] = fmaf(a.x, b.y, acc[0][1]);
      acc[0][2] = fmaf(a.x, b.z, acc[0][2]);
      acc[0][3] = fmaf(a.x, b.w, acc[0][3]);
      acc[1][0] = fmaf(a.y, b.x, acc[1][0]);
      acc[1][1] = fmaf(a.y, b.y, acc[1][1]);
      acc[1][2] = fmaf(a.y, b.z, acc[1][2]);
      acc[1][3] = fmaf(a.y, b.w, acc[1][3]);
    }
    __syncthreads();
  }

#pragma unroll
  for (int i = 0; i < 2; ++i) {
    int row = row0 + ty * 2 + i;
    if (row >= KDIM) continue;
    int idx = row * PP + col0 + tx * 4;
    float4 cmv = *reinterpret_cast<const float4*>(&cm[idx]);
    float4 cpv = *reinterpret_cast<const float4*>(&cp[idx]);
    float4 xov = *reinterpret_cast<const float4*>(&xin[idx]);
    float4 xn, yn;
    float c;
    c = acc[i][0]; xn.x = fmaxf(0.f, c + cmv.x) + fminf(0.f, c + cpv.x); yn.x = xn.x + mu * (xn.x - xov.x);
    c = acc[i][1]; xn.y = fmaxf(0.f, c + cmv.y) + fminf(0.f, c + cpv.y); yn.y = xn.y + mu * (xn.y - xov.y);
    c = acc[i][2]; xn.z = fmaxf(0.f, c + cmv.z) + fminf(0.f, c + cpv.z); yn.z = xn.z + mu * (xn.z - xov.z);
    c = acc[i][3]; xn.w = fmaxf(0.f, c + cmv.w) + fminf(0.f, c + cpv.w); yn.w = xn.w + mu * (xn.w - xov.w);
    *reinterpret_cast<float4*>(&xout[idx]) = xn;
    *reinterpret_cast<float4*>(&yout[idx]) = yn;
  }
}

// ---------------- reweighting: wr = 1/(|x|+eps), partial sums of wr^2 ----------------
__global__ void k_wr(const float* __restrict__ x, float* __restrict__ w,
                     float* __restrict__ part) {
  __shared__ float sm[256];
  int idx = blockIdx.x * 256 + threadIdx.x;
  float v = 1.0f / (fabsf(x[idx]) + EPSW);
  w[idx] = v;
  sm[threadIdx.x] = v * v;
  __syncthreads();
  for (int s = 128; s > 0; s >>= 1) {
    if (threadIdx.x < s) sm[threadIdx.x] += sm[threadIdx.x + s];
    __syncthreads();
  }
  if (threadIdx.x == 0) part[blockIdx.x] = sm[0];
}

__global__ void k_wred(const float* __restrict__ part, float* __restrict__ Lb) {
  __shared__ float sm[256];
  float s = 0.0f;
  for (int i = threadIdx.x; i < 1282; i += 256) s += part[i];
  sm[threadIdx.x] = s;
  __syncthreads();
  for (int st = 128; st > 0; st >>= 1) {
    if (threadIdx.x < st) sm[threadIdx.x] += sm[threadIdx.x + st];
    __syncthreads();
  }
  if (threadIdx.x == 0) Lb[2] = 1.0f / sqrtf(sm[0]);
}

// ---------------- host ----------------
extern "C" void kernel_launch(void* const* d_in, const int* in_sizes, int n_in,
                              void* d_out, int out_size, void* d_ws, size_t ws_size,
                              hipStream_t stream) {
  const float* x  = (const float*)d_in[0];
  const float* rr = (const float*)d_in[1];
  const float* th = (const float*)d_in[2];
  float* out = (float*)d_out;
  float* ws  = (float*)d_ws;

  size_t off = 0;
  auto alloc = [&](size_t n) {
    float* p = ws + off;
    off += (n + 63) & ~(size_t)63;
    return p;
  };
  float* D    = alloc(TT * KDIM);
  float* A    = alloc((size_t)KDIM * LDA);
  float* G    = alloc(TT * TT);
  float* Lb   = alloc(16);
  float* c0   = alloc((size_t)KDIM * PP);
  float* cm   = alloc((size_t)KDIM * PP);
  float* cp   = alloc((size_t)KDIM * PP);
  float* xa   = alloc((size_t)KDIM * PP);
  float* xb   = alloc((size_t)KDIM * PP);
  float* ya   = alloc((size_t)KDIM * PP);
  float* yb   = alloc((size_t)KDIM * PP);
  float* w    = alloc((size_t)KDIM * PP);
  float* part = alloc(1312);
  if (off * sizeof(float) > ws_size) return;  // workspace too small: fail loudly

  // FISTA momentum schedule (pure scalar host math; deterministic)
  float mu[NITER];
  {
    float t = 1.0f;
    for (int i = 0; i < NITER; ++i) {
      float tn = (1.0f + sqrtf(1.0f + 4.0f * t * t)) * 0.5f;
      mu[i] = (t - 1.0f) / tn;
      t = tn;
    }
  }

  k_build_dic<<<(TT * KDIM + 255) / 256, 256, 0, stream>>>(rr, th, D, out + (size_t)KDIM * PP);
  k_G<<<(TT * TT + 255) / 256, 256, 0, stream>>>(D, G);
  k_power<<<1, 64, 0, stream>>>(G, Lb);
  k_A<<<(KDIM * LDA + 255) / 256, 256, 0, stream>>>(D, Lb, A);
  k_c0<<<(KDIM * PP) / 256, 256, 0, stream>>>(D, x, Lb, c0);

  dim3 fgrid(PP / BN, (KDIM + BM - 1) / BM);
  for (int r = 0; r < 3; ++r) {
    k_c<<<(KDIM * PP) / 256, 256, 0, stream>>>(c0, w, Lb, cm, cp, xa, ya, r == 0 ? 1 : 0);
    for (int i = 0; i < NITER; ++i) {
      float* yi = (i & 1) ? yb : ya;
      float* xi = (i & 1) ? xb : xa;
      float* yo = (i & 1) ? ya : yb;
      float* xo = (i & 1) ? xa : xb;
      if (r == 2 && i == NITER - 1) xo = out;  // last iterate lands in d_out
      k_fista<<<fgrid, 256, 0, stream>>>(A, yi, xi, cm, cp, xo, yo, mu[i]);
    }
    if (r < 2) {
      k_wr<<<1282, 256, 0, stream>>>(xa, w, part);
      k_wred<<<1, 256, 0, stream>>>(part, Lb);
    }
  }
}

// Round 2
// 2195.784 us; speedup vs baseline: 7.5940x; 7.5940x over previous
//
#include <hip/hip_runtime.h>
#include <math.h>

#define TT 36
#define NP 160
#define KDIM 641
#define PP 512
#define KP 644            // padded K (multiple of 4), pad rows stay zero
#define NQ 161            // ceil(641/4) quads
#define LAM 0.1f
#define EPSW 0.01f
#define NITER 200
#define NPOW 600

// ---------------- dictionary ----------------
__global__ void k_build_dic(const float* __restrict__ rr, const float* __restrict__ th,
                            float* __restrict__ D, float* __restrict__ outD) {
  int idx = blockIdx.x * blockDim.x + threadIdx.x;
  if (idx >= TT * KDIM) return;
  int t = idx / KDIM, k = idx % KDIM;
  float v;
  if (k == 0) {
    v = 1.0f;
  } else {
    int g = (k - 1) / NP;     // 0:p*cos 1:m*cos 2:p*sin 3:m*sin
    int p = (k - 1) % NP;
    float ft = (float)t;
    float pw = powf(rr[p], ft);
    if ((g == 1 || g == 3) && (t & 1)) pw = -pw;
    float ang = ft * th[p];
    v = pw * ((g < 2) ? cosf(ang) : sinf(ang));
  }
  D[idx] = v;
  outD[idx] = v;
}

// ---------------- G = D D^T (36x36) ----------------
__global__ void k_G(const float* __restrict__ D, float* __restrict__ G) {
  int idx = blockIdx.x * blockDim.x + threadIdx.x;
  if (idx >= TT * TT) return;
  int i = idx / TT, j = idx % TT;
  float s = 0.0f;
  for (int k = 0; k < KDIM; ++k) s = fmaf(D[i * KDIM + k], D[j * KDIM + k], s);
  G[idx] = s;
}

// ---------------- power iteration on 36x36 (one wave): L = ||DtD||_2 ----------------
__global__ void k_power(const float* __restrict__ G, float* __restrict__ Lb) {
  int lane = threadIdx.x;   // blockDim = 64
  float g[TT];
#pragma unroll
  for (int j = 0; j < TT; ++j) g[j] = (lane < TT) ? G[lane * TT + j] : 0.0f;
  float v = (lane < TT) ? 1.0f : 0.0f;
  for (int it = 0; it < NPOW; ++it) {
    float u = 0.0f;
#pragma unroll
    for (int j = 0; j < TT; ++j) u = fmaf(g[j], __shfl(v, j, 64), u);
    float s = u * u;
#pragma unroll
    for (int o = 32; o >= 1; o >>= 1) s += __shfl_xor(s, o, 64);
    v = u * rsqrtf(s);
  }
  float u = 0.0f;
#pragma unroll
  for (int j = 0; j < TT; ++j) u = fmaf(g[j], __shfl(v, j, 64), u);
  float num = v * u, den = v * v;
#pragma unroll
  for (int o = 32; o >= 1; o >>= 1) {
    num += __shfl_xor(num, o, 64);
    den += __shfl_xor(den, o, 64);
  }
  if (lane == 0) {
    float L = num / den;   // Rayleigh quotient = lambda_max
    Lb[0] = L;
    Lb[1] = 1.0f / L;
  }
}

// ---------------- persistent per-round FISTA (columns p0, p0+1) ----------------
__global__ __launch_bounds__(256, 1) void k_round(
    const float* __restrict__ Dg, const float* __restrict__ X,
    const float* __restrict__ Lb, const float* __restrict__ w,
    float* __restrict__ xout, int first) {
  __shared__ __align__(16) float ylds[KP][2];
  __shared__ __align__(16) float zlds[TT][2];

  const int tid  = threadIdx.x;
  const int lane = tid & 63;
  const int g    = tid >> 6;          // wave id 0..3
  const int i0   = g * 9;             // this wave's z-rows: i0..i0+8
  const int p0   = blockIdx.x * 2;

  const float Linv = Lb[1];
  const float lamL = LAM * Linv;

  const int r1 = tid;
  const int r2 = tid + 256;
  const int r3 = tid + 512;
  const bool has3 = (r3 < KDIM);      // tid < 129

  // ---- phase-1 D slice in registers: Dq[ii][4j+kk] = D[i0+ii][4*(lane+64j)+kk]
  float Dq[9][12];
#pragma unroll
  for (int ii = 0; ii < 9; ++ii)
#pragma unroll
    for (int j = 0; j < 3; ++j)
#pragma unroll
      for (int kk = 0; kk < 4; ++kk) {
        const int q = lane + 64 * j;
        const int k = 4 * q + kk;
        const bool ok = (q < NQ) && (k < KDIM);
        Dq[ii][4 * j + kk] = ok ? Dg[(i0 + ii) * KDIM + k] : 0.0f;
      }

  // ---- phase-2 D columns in registers (rows r1, r2, r3)
  float Dc1[TT], Dc2[TT], Dc3[TT];
#pragma unroll
  for (int i = 0; i < TT; ++i) {
    Dc1[i] = Dg[i * KDIM + r1];
    Dc2[i] = Dg[i * KDIM + r2];
    Dc3[i] = has3 ? Dg[i * KDIM + r3] : 0.0f;
  }

  // ---- c0 = Linv * (D^T X) for owned rows; cm/cp thresholds
  float cm1[2], cp1[2], cm2[2], cp2[2], cm3[2], cp3[2];
  {
    float s1[2] = {0.f, 0.f}, s2[2] = {0.f, 0.f}, s3[2] = {0.f, 0.f};
#pragma unroll
    for (int i = 0; i < TT; ++i) {
      const float xv0 = X[i * PP + p0];
      const float xv1 = X[i * PP + p0 + 1];
      s1[0] = fmaf(Dc1[i], xv0, s1[0]); s1[1] = fmaf(Dc1[i], xv1, s1[1]);
      s2[0] = fmaf(Dc2[i], xv0, s2[0]); s2[1] = fmaf(Dc2[i], xv1, s2[1]);
      s3[0] = fmaf(Dc3[i], xv0, s3[0]); s3[1] = fmaf(Dc3[i], xv1, s3[1]);
    }
    const float nrm = first ? 0.0f : Lb[2];
#pragma unroll
    for (int c = 0; c < 2; ++c) {
      float wl1 = lamL, wl2 = lamL, wl3 = lamL;
      if (!first) {
        wl1 = w[r1 * PP + p0 + c] * nrm * lamL;
        wl2 = w[r2 * PP + p0 + c] * nrm * lamL;
        wl3 = has3 ? (w[r3 * PP + p0 + c] * nrm * lamL) : 0.0f;
      }
      const float c01 = s1[c] * Linv, c02 = s2[c] * Linv, c03 = s3[c] * Linv;
      cm1[c] = c01 - wl1; cp1[c] = c01 + wl1;
      cm2[c] = c02 - wl2; cp2[c] = c02 + wl2;
      cm3[c] = c03 - wl3; cp3[c] = c03 + wl3;
    }
  }

  // ---- zero y in LDS (including pad rows 641..643, which must stay 0)
  for (int idx = tid; idx < KP * 2; idx += 256) ((float*)ylds)[idx] = 0.0f;

  float x1[2] = {0.f, 0.f}, x2[2] = {0.f, 0.f}, x3[2] = {0.f, 0.f};
  float y1[2] = {0.f, 0.f}, y2[2] = {0.f, 0.f}, y3[2] = {0.f, 0.f};
  float tmom = 1.0f;

  __syncthreads();

  for (int it = 0; it < NITER; ++it) {
    // ===== phase 1: z = Linv * (D @ y); per-wave partials + butterfly =====
    float acc[9][2];
#pragma unroll
    for (int ii = 0; ii < 9; ++ii) { acc[ii][0] = 0.f; acc[ii][1] = 0.f; }
#pragma unroll
    for (int j = 0; j < 3; ++j) {
      const int q = lane + 64 * j;
      if (j < 2 || q < NQ) {
        const float4 ya = *reinterpret_cast<const float4*>(&ylds[4 * q][0]);
        const float4 yb = *reinterpret_cast<const float4*>(&ylds[4 * q + 2][0]);
#pragma unroll
        for (int ii = 0; ii < 9; ++ii) {
          acc[ii][0] += Dq[ii][4*j+0] * ya.x + Dq[ii][4*j+1] * ya.z
                      + Dq[ii][4*j+2] * yb.x + Dq[ii][4*j+3] * yb.z;
          acc[ii][1] += Dq[ii][4*j+0] * ya.y + Dq[ii][4*j+1] * ya.w
                      + Dq[ii][4*j+2] * yb.y + Dq[ii][4*j+3] * yb.w;
        }
      }
    }
#pragma unroll
    for (int ii = 0; ii < 9; ++ii)
#pragma unroll
      for (int c = 0; c < 2; ++c) {
        float v = acc[ii][c];
        v += __shfl_xor(v, 1, 64);
        v += __shfl_xor(v, 2, 64);
        v += __shfl_xor(v, 4, 64);
        v += __shfl_xor(v, 8, 64);
        v += __shfl_xor(v, 16, 64);
        v += __shfl_xor(v, 32, 64);
        acc[ii][c] = v;
      }
    if (lane == 0) {
#pragma unroll
      for (int ii = 0; ii < 9; ++ii) {
        zlds[i0 + ii][0] = acc[ii][0] * Linv;
        zlds[i0 + ii][1] = acc[ii][1] * Linv;
      }
    }
    __syncthreads();

    // ===== phase 2: u = y - D^T z; shrink; momentum =====
    const float tn = 0.5f * (1.0f + sqrtf(1.0f + 4.0f * tmom * tmom));
    const float mu = (tmom - 1.0f) / tn;
    tmom = tn;

    float s10 = 0.f, s11 = 0.f, s20 = 0.f, s21 = 0.f, s30 = 0.f, s31 = 0.f;
#pragma unroll
    for (int i = 0; i < TT; ++i) {
      const float2 zv = *reinterpret_cast<const float2*>(&zlds[i][0]);
      s10 = fmaf(Dc1[i], zv.x, s10); s11 = fmaf(Dc1[i], zv.y, s11);
      s20 = fmaf(Dc2[i], zv.x, s20); s21 = fmaf(Dc2[i], zv.y, s21);
      s30 = fmaf(Dc3[i], zv.x, s30); s31 = fmaf(Dc3[i], zv.y, s31);
    }
    {
      float u, xn;
      u = y1[0] - s10; xn = fmaxf(0.f, u + cm1[0]) + fminf(0.f, u + cp1[0]);
      y1[0] = xn + mu * (xn - x1[0]); x1[0] = xn;
      u = y1[1] - s11; xn = fmaxf(0.f, u + cm1[1]) + fminf(0.f, u + cp1[1]);
      y1[1] = xn + mu * (xn - x1[1]); x1[1] = xn;
      u = y2[0] - s20; xn = fmaxf(0.f, u + cm2[0]) + fminf(0.f, u + cp2[0]);
      y2[0] = xn + mu * (xn - x2[0]); x2[0] = xn;
      u = y2[1] - s21; xn = fmaxf(0.f, u + cm2[1]) + fminf(0.f, u + cp2[1]);
      y2[1] = xn + mu * (xn - x2[1]); x2[1] = xn;
      if (has3) {
        u = y3[0] - s30; xn = fmaxf(0.f, u + cm3[0]) + fminf(0.f, u + cp3[0]);
        y3[0] = xn + mu * (xn - x3[0]); x3[0] = xn;
        u = y3[1] - s31; xn = fmaxf(0.f, u + cm3[1]) + fminf(0.f, u + cp3[1]);
        y3[1] = xn + mu * (xn - x3[1]); x3[1] = xn;
      }
      *reinterpret_cast<float2*>(&ylds[r1][0]) = make_float2(y1[0], y1[1]);
      *reinterpret_cast<float2*>(&ylds[r2][0]) = make_float2(y2[0], y2[1]);
      if (has3) *reinterpret_cast<float2*>(&ylds[r3][0]) = make_float2(y3[0], y3[1]);
    }
    __syncthreads();
  }

  *reinterpret_cast<float2*>(&xout[r1 * PP + p0]) = make_float2(x1[0], x1[1]);
  *reinterpret_cast<float2*>(&xout[r2 * PP + p0]) = make_float2(x2[0], x2[1]);
  if (has3) *reinterpret_cast<float2*>(&xout[r3 * PP + p0]) = make_float2(x3[0], x3[1]);
}

// ---------------- reweighting: wr = 1/(|x|+eps), partial sums of wr^2 ----------------
__global__ void k_wr(const float* __restrict__ x, float* __restrict__ w,
                     float* __restrict__ part) {
  __shared__ float sm[256];
  int idx = blockIdx.x * 256 + threadIdx.x;
  float v = 1.0f / (fabsf(x[idx]) + EPSW);
  w[idx] = v;
  sm[threadIdx.x] = v * v;
  __syncthreads();
  for (int s = 128; s > 0; s >>= 1) {
    if (threadIdx.x < s) sm[threadIdx.x] += sm[threadIdx.x + s];
    __syncthreads();
  }
  if (threadIdx.x == 0) part[blockIdx.x] = sm[0];
}

__global__ void k_wred(const float* __restrict__ part, float* __restrict__ Lb) {
  __shared__ float sm[256];
  float s = 0.0f;
  for (int i = threadIdx.x; i < 1282; i += 256) s += part[i];
  sm[threadIdx.x] = s;
  __syncthreads();
  for (int st = 128; st > 0; st >>= 1) {
    if (threadIdx.x < st) sm[threadIdx.x] += sm[threadIdx.x + st];
    __syncthreads();
  }
  if (threadIdx.x == 0) Lb[2] = 1.0f / sqrtf(sm[0]);
}

// ---------------- host ----------------
extern "C" void kernel_launch(void* const* d_in, const int* in_sizes, int n_in,
                              void* d_out, int out_size, void* d_ws, size_t ws_size,
                              hipStream_t stream) {
  const float* x  = (const float*)d_in[0];
  const float* rr = (const float*)d_in[1];
  const float* th = (const float*)d_in[2];
  float* out = (float*)d_out;
  float* ws  = (float*)d_ws;

  size_t off = 0;
  auto alloc = [&](size_t n) {
    float* p = ws + off;
    off += (n + 63) & ~(size_t)63;
    return p;
  };
  float* D    = alloc((size_t)TT * KDIM);
  float* G    = alloc(TT * TT);
  float* Lb   = alloc(16);
  float* xa   = alloc((size_t)KDIM * PP);
  float* w    = alloc((size_t)KDIM * PP);
  float* part = alloc(1312);
  if (off * sizeof(float) > ws_size) return;  // workspace too small

  k_build_dic<<<(TT * KDIM + 255) / 256, 256, 0, stream>>>(rr, th, D, out + (size_t)KDIM * PP);
  k_G<<<(TT * TT + 255) / 256, 256, 0, stream>>>(D, G);
  k_power<<<1, 64, 0, stream>>>(G, Lb);

  for (int r = 0; r < 3; ++r) {
    float* xo = (r == 2) ? out : xa;
    k_round<<<PP / 2, 256, 0, stream>>>(D, x, Lb, w, xo, r == 0 ? 1 : 0);
    if (r < 2) {
      k_wr<<<(KDIM * PP) / 256, 256, 0, stream>>>(xa, w, part);
      k_wred<<<1, 256, 0, stream>>>(part, Lb);
    }
  }
}

// Round 3
// 1433.783 us; speedup vs baseline: 11.6298x; 1.5315x over previous
//
#include <hip/hip_runtime.h>
#include <math.h>

#define TT 36
#define NP 160
#define KDIM 641
#define PP 512
#define KPAD 704          // 64*11, LDS y padded; pads stay zero
#define LAM 0.1f
#define EPSW 0.01f
#define NITER 200
#define NPOW 300

// ---------------- dictionary ----------------
__global__ void k_build_dic(const float* __restrict__ rr, const float* __restrict__ th,
                            float* __restrict__ D, float* __restrict__ outD) {
  int idx = blockIdx.x * blockDim.x + threadIdx.x;
  if (idx >= TT * KDIM) return;
  int t = idx / KDIM, k = idx % KDIM;
  float v;
  if (k == 0) {
    v = 1.0f;
  } else {
    int g = (k - 1) / NP;     // 0:p*cos 1:m*cos 2:p*sin 3:m*sin
    int p = (k - 1) % NP;
    float ft = (float)t;
    float pw = powf(rr[p], ft);
    if ((g == 1 || g == 3) && (t & 1)) pw = -pw;
    float ang = ft * th[p];
    v = pw * ((g < 2) ? cosf(ang) : sinf(ang));
  }
  D[idx] = v;
  outD[idx] = v;
}

// ---------------- G = D D^T (36x36) ----------------
__global__ void k_G(const float* __restrict__ D, float* __restrict__ G) {
  int idx = blockIdx.x * blockDim.x + threadIdx.x;
  if (idx >= TT * TT) return;
  int i = idx / TT, j = idx % TT;
  float s = 0.0f;
  for (int k = 0; k < KDIM; ++k) s = fmaf(D[i * KDIM + k], D[j * KDIM + k], s);
  G[idx] = s;
}

// ---------------- power iteration on 36x36 (one wave): L = ||DtD||_2 ----------------
__global__ void k_power(const float* __restrict__ G, float* __restrict__ Lb) {
  int lane = threadIdx.x;   // blockDim = 64
  float g[TT];
#pragma unroll
  for (int j = 0; j < TT; ++j) g[j] = (lane < TT) ? G[lane * TT + j] : 0.0f;
  float v = (lane < TT) ? 1.0f : 0.0f;
  for (int it = 0; it < NPOW; ++it) {
    float u = 0.0f;
#pragma unroll
    for (int j = 0; j < TT; ++j) u = fmaf(g[j], __shfl(v, j, 64), u);
    float s = u * u;
#pragma unroll
    for (int o = 32; o >= 1; o >>= 1) s += __shfl_xor(s, o, 64);
    v = u * rsqrtf(s);
  }
  float u = 0.0f;
#pragma unroll
  for (int j = 0; j < TT; ++j) u = fmaf(g[j], __shfl(v, j, 64), u);
  float num = v * u, den = v * v;
#pragma unroll
  for (int o = 32; o >= 1; o >>= 1) {
    num += __shfl_xor(num, o, 64);
    den += __shfl_xor(den, o, 64);
  }
  if (lane == 0) {
    float L = num / den;   // Rayleigh quotient = lambda_max
    Lb[0] = L;
    Lb[1] = 1.0f / L;
  }
}

// ---------------- persistent per-round FISTA: ONE column per block ----------------
__global__ __launch_bounds__(256, 2) void k_round(
    const float* __restrict__ Dg, const float* __restrict__ X,
    const float* __restrict__ Lb, const float* __restrict__ w,
    float* __restrict__ xout, int first) {
  __shared__ __align__(16) float ylds[KPAD];
  __shared__ __align__(16) float zlds[TT];

  const int tid  = threadIdx.x;
  const int lane = tid & 63;
  const int g    = tid >> 6;          // wave id 0..3
  const int i0   = g * 9;             // this wave's z-rows: i0..i0+8
  const int p    = blockIdx.x;        // column

  const float Linv = Lb[1];
  const float lamL = LAM * Linv;

  const int r1 = tid;
  const int r2 = tid + 256;
  const int r3 = tid + 512;
  const bool has3 = (r3 < KDIM);      // tid < 129

  // ---- phase-1 D slice in registers: Dq[ii][j] = D[i0+ii][lane + 64j] (coalesced)
  float Dq[9][11];
#pragma unroll
  for (int ii = 0; ii < 9; ++ii)
#pragma unroll
    for (int j = 0; j < 11; ++j) {
      const int k = lane + 64 * j;
      Dq[ii][j] = (k < KDIM) ? Dg[(i0 + ii) * KDIM + k] : 0.0f;
    }

  // ---- phase-2 D columns in registers (rows r1, r2, r3) — coalesced across lanes
  float Dc1[TT], Dc2[TT], Dc3[TT];
#pragma unroll
  for (int i = 0; i < TT; ++i) {
    Dc1[i] = Dg[i * KDIM + r1];
    Dc2[i] = Dg[i * KDIM + r2];
    Dc3[i] = has3 ? Dg[i * KDIM + r3] : 0.0f;
  }

  // ---- c0 = Linv * (D^T x_col); cm/cp thresholds
  float cm1, cp1, cm2, cp2, cm3, cp3;
  {
    float s1 = 0.f, s2 = 0.f, s3 = 0.f;
#pragma unroll
    for (int i = 0; i < TT; ++i) {
      const float xv = X[i * PP + p];
      s1 = fmaf(Dc1[i], xv, s1);
      s2 = fmaf(Dc2[i], xv, s2);
      s3 = fmaf(Dc3[i], xv, s3);
    }
    float wl1 = lamL, wl2 = lamL, wl3 = lamL;
    if (!first) {
      const float nl = Lb[2] * lamL;   // (1/||wr||) * lam * Linv
      wl1 = w[r1 * PP + p] * nl;
      wl2 = w[r2 * PP + p] * nl;
      wl3 = has3 ? (w[r3 * PP + p] * nl) : 0.0f;
    }
    const float c01 = s1 * Linv, c02 = s2 * Linv, c03 = s3 * Linv;
    cm1 = c01 - wl1; cp1 = c01 + wl1;
    cm2 = c02 - wl2; cp2 = c02 + wl2;
    cm3 = c03 - wl3; cp3 = c03 + wl3;
  }

  // ---- zero y in LDS (incl. pad rows 641..703, must stay 0)
  for (int idx = tid; idx < KPAD; idx += 256) ylds[idx] = 0.0f;

  float x1 = 0.f, x2 = 0.f, x3 = 0.f;
  float y1 = 0.f, y2 = 0.f, y3 = 0.f;
  float tmom = 1.0f;

  __syncthreads();

  for (int it = 0; it < NITER; ++it) {
    // ===== phase 1: z = Linv * (D @ y) =====
    float acc[9];
#pragma unroll
    for (int ii = 0; ii < 9; ++ii) acc[ii] = 0.f;
#pragma unroll
    for (int j = 0; j < 11; ++j) {
      const float yv = ylds[lane + 64 * j];   // stride-64 b32: conflict-free
#pragma unroll
      for (int ii = 0; ii < 9; ++ii) acc[ii] = fmaf(Dq[ii][j], yv, acc[ii]);
    }
#pragma unroll
    for (int ii = 0; ii < 9; ++ii) {
      float v = acc[ii];
      v += __shfl_xor(v, 1, 64);
      v += __shfl_xor(v, 2, 64);
      v += __shfl_xor(v, 4, 64);
      v += __shfl_xor(v, 8, 64);
      v += __shfl_xor(v, 16, 64);
      v += __shfl_xor(v, 32, 64);
      acc[ii] = v;
    }
    if (lane == 0) {
#pragma unroll
      for (int ii = 0; ii < 9; ++ii) zlds[i0 + ii] = acc[ii] * Linv;
    }
    __syncthreads();

    // ===== phase 2: u = y - D^T z; shrink; momentum =====
    const float tn = 0.5f * (1.0f + sqrtf(1.0f + 4.0f * tmom * tmom));
    const float mu = (tmom - 1.0f) / tn;
    tmom = tn;

    float s1 = 0.f, s2 = 0.f, s3 = 0.f;
#pragma unroll
    for (int q = 0; q < 9; ++q) {
      const float4 z4 = *reinterpret_cast<const float4*>(&zlds[4 * q]);  // broadcast
      s1 = fmaf(Dc1[4*q+0], z4.x, s1); s1 = fmaf(Dc1[4*q+1], z4.y, s1);
      s1 = fmaf(Dc1[4*q+2], z4.z, s1); s1 = fmaf(Dc1[4*q+3], z4.w, s1);
      s2 = fmaf(Dc2[4*q+0], z4.x, s2); s2 = fmaf(Dc2[4*q+1], z4.y, s2);
      s2 = fmaf(Dc2[4*q+2], z4.z, s2); s2 = fmaf(Dc2[4*q+3], z4.w, s2);
      s3 = fmaf(Dc3[4*q+0], z4.x, s3); s3 = fmaf(Dc3[4*q+1], z4.y, s3);
      s3 = fmaf(Dc3[4*q+2], z4.z, s3); s3 = fmaf(Dc3[4*q+3], z4.w, s3);
    }
    {
      float u, xn;
      u = y1 - s1; xn = fmaxf(0.f, u + cm1) + fminf(0.f, u + cp1);
      y1 = xn + mu * (xn - x1); x1 = xn;
      u = y2 - s2; xn = fmaxf(0.f, u + cm2) + fminf(0.f, u + cp2);
      y2 = xn + mu * (xn - x2); x2 = xn;
      u = y3 - s3; xn = fmaxf(0.f, u + cm3) + fminf(0.f, u + cp3);
      y3 = xn + mu * (xn - x3); x3 = xn;
      ylds[r1] = y1;
      ylds[r2] = y2;
      if (has3) ylds[r3] = y3;
    }
    __syncthreads();
  }

  xout[r1 * PP + p] = x1;
  xout[r2 * PP + p] = x2;
  if (has3) xout[r3 * PP + p] = x3;
}

// ---------------- reweighting: wr = 1/(|x|+eps), partial sums of wr^2 ----------------
__global__ void k_wr(const float* __restrict__ x, float* __restrict__ w,
                     float* __restrict__ part) {
  __shared__ float sm[256];
  int idx = blockIdx.x * 256 + threadIdx.x;
  float v = 1.0f / (fabsf(x[idx]) + EPSW);
  w[idx] = v;
  sm[threadIdx.x] = v * v;
  __syncthreads();
  for (int s = 128; s > 0; s >>= 1) {
    if (threadIdx.x < s) sm[threadIdx.x] += sm[threadIdx.x + s];
    __syncthreads();
  }
  if (threadIdx.x == 0) part[blockIdx.x] = sm[0];
}

__global__ void k_wred(const float* __restrict__ part, float* __restrict__ Lb) {
  __shared__ float sm[256];
  float s = 0.0f;
  for (int i = threadIdx.x; i < 1282; i += 256) s += part[i];
  sm[threadIdx.x] = s;
  __syncthreads();
  for (int st = 128; st > 0; st >>= 1) {
    if (threadIdx.x < st) sm[threadIdx.x] += sm[threadIdx.x + st];
    __syncthreads();
  }
  if (threadIdx.x == 0) Lb[2] = 1.0f / sqrtf(sm[0]);
}

// ---------------- host ----------------
extern "C" void kernel_launch(void* const* d_in, const int* in_sizes, int n_in,
                              void* d_out, int out_size, void* d_ws, size_t ws_size,
                              hipStream_t stream) {
  const float* x  = (const float*)d_in[0];
  const float* rr = (const float*)d_in[1];
  const float* th = (const float*)d_in[2];
  float* out = (float*)d_out;
  float* ws  = (float*)d_ws;

  size_t off = 0;
  auto alloc = [&](size_t n) {
    float* p = ws + off;
    off += (n + 63) & ~(size_t)63;
    return p;
  };
  float* D    = alloc((size_t)TT * KDIM);
  float* G    = alloc(TT * TT);
  float* Lb   = alloc(16);
  float* xa   = alloc((size_t)KDIM * PP);
  float* w    = alloc((size_t)KDIM * PP);
  float* part = alloc(1312);
  if (off * sizeof(float) > ws_size) return;  // workspace too small

  k_build_dic<<<(TT * KDIM + 255) / 256, 256, 0, stream>>>(rr, th, D, out + (size_t)KDIM * PP);
  k_G<<<(TT * TT + 255) / 256, 256, 0, stream>>>(D, G);
  k_power<<<1, 64, 0, stream>>>(G, Lb);

  for (int r = 0; r < 3; ++r) {
    float* xo = (r == 2) ? out : xa;
    k_round<<<PP, 256, 0, stream>>>(D, x, Lb, w, xo, r == 0 ? 1 : 0);
    if (r < 2) {
      k_wr<<<(KDIM * PP) / 256, 256, 0, stream>>>(xa, w, part);
      k_wred<<<1, 256, 0, stream>>>(part, Lb);
    }
  }
}

// Round 4
// 1006.561 us; speedup vs baseline: 16.5660x; 1.4244x over previous
//
#include <hip/hip_runtime.h>
#include <math.h>

#define TT 36
#define NP 160
#define KDIM 641
#define PP 512
#define KPAD 704          // LDS y padded; pads stay zero (used as zero source)
#define ZPAD 664          // any index in 641..703: guaranteed-zero slot
#define LAM 0.1f
#define EPSW 0.01f
#define NITER 200
#define NPOW 300

// ---------------- dictionary ----------------
__global__ void k_build_dic(const float* __restrict__ rr, const float* __restrict__ th,
                            float* __restrict__ D, float* __restrict__ outD) {
  int idx = blockIdx.x * blockDim.x + threadIdx.x;
  if (idx >= TT * KDIM) return;
  int t = idx / KDIM, k = idx % KDIM;
  float v;
  if (k == 0) {
    v = 1.0f;
  } else {
    int g = (k - 1) / NP;     // 0:p*cos 1:m*cos 2:p*sin 3:m*sin
    int p = (k - 1) % NP;
    float ft = (float)t;
    float pw = powf(rr[p], ft);
    if ((g == 1 || g == 3) && (t & 1)) pw = -pw;
    float ang = ft * th[p];
    v = pw * ((g < 2) ? cosf(ang) : sinf(ang));
  }
  D[idx] = v;
  outD[idx] = v;
}

// ---------------- G = D D^T (36x36) ----------------
__global__ void k_G(const float* __restrict__ D, float* __restrict__ G) {
  int idx = blockIdx.x * blockDim.x + threadIdx.x;
  if (idx >= TT * TT) return;
  int i = idx / TT, j = idx % TT;
  float s = 0.0f;
  for (int k = 0; k < KDIM; ++k) s = fmaf(D[i * KDIM + k], D[j * KDIM + k], s);
  G[idx] = s;
}

// ---------------- power iteration on 36x36 (one wave): L = ||DtD||_2 ----------------
__global__ void k_power(const float* __restrict__ G, float* __restrict__ Lb) {
  int lane = threadIdx.x;   // blockDim = 64
  float g[TT];
#pragma unroll
  for (int j = 0; j < TT; ++j) g[j] = (lane < TT) ? G[lane * TT + j] : 0.0f;
  float v = (lane < TT) ? 1.0f : 0.0f;
  for (int it = 0; it < NPOW; ++it) {
    float u = 0.0f;
#pragma unroll
    for (int j = 0; j < TT; ++j) u = fmaf(g[j], __shfl(v, j, 64), u);
    float s = u * u;
#pragma unroll
    for (int o = 32; o >= 1; o >>= 1) s += __shfl_xor(s, o, 64);
    v = u * rsqrtf(s);
  }
  float u = 0.0f;
#pragma unroll
  for (int j = 0; j < TT; ++j) u = fmaf(g[j], __shfl(v, j, 64), u);
  float num = v * u, den = v * v;
#pragma unroll
  for (int o = 32; o >= 1; o >>= 1) {
    num += __shfl_xor(num, o, 64);
    den += __shfl_xor(den, o, 64);
  }
  if (lane == 0) {
    float L = num / den;   // Rayleigh quotient = lambda_max
    Lb[0] = L;
    Lb[1] = 1.0f / L;
  }
}

// ---- DPP wave-64 sum: after 6 steps lanes 48..63 hold the total ----
template <int C>
__device__ __forceinline__ float dppadd(float v) {
  int t = __builtin_amdgcn_update_dpp(0, __float_as_int(v), C, 0xf, 0xf, true);
  return v + __int_as_float(t);
}
__device__ __forceinline__ float wave_sum63(float v) {
  v = dppadd<0xB1>(v);    // quad_perm [1,0,3,2]  (xor 1)
  v = dppadd<0x4E>(v);    // quad_perm [2,3,0,1]  (xor 2)
  v = dppadd<0x141>(v);   // row_half_mirror      (xor 4 equiv)
  v = dppadd<0x140>(v);   // row_mirror           (xor 8 equiv)
  v = dppadd<0x142>(v);   // row_bcast15
  v = dppadd<0x143>(v);   // row_bcast31
  return v;               // valid in lane 63
}

// ---------------- persistent per-round FISTA: ONE column per block ----------------
__global__ __attribute__((amdgpu_flat_work_group_size(256, 256), amdgpu_waves_per_eu(2, 2)))
void k_round(
    const float* __restrict__ Dg, const float* __restrict__ X,
    const float* __restrict__ Lb, const float* __restrict__ w,
    float* __restrict__ xout, int first) {
  __shared__ __align__(16) float ylds[KPAD];
  __shared__ __align__(16) float zlds[TT];

  const int tid  = threadIdx.x;
  const int lane = tid & 63;
  const int g    = tid >> 6;          // wave id 0..3
  const int i0   = g * 9;             // this wave's z-rows: i0..i0+8
  const bool gOdd = (g & 1);
  const int p    = blockIdx.x;        // column

  const float Linv = Lb[1];
  const float lamL = LAM * Linv;

  const int r1 = tid;
  const int r2 = tid + 256;
  const int r3 = tid + 512;
  const bool has3 = (r3 < KDIM);      // tid < 129

  // ---- phase-1 pole-paired units: u = lane + 64j, j<6 covers 321 units
  //   u==0        : constant column k=0
  //   1<=u<161    : cos-pole p=u-1   -> kA=u,     kB=u+160
  //   161<=u<321  : sin-pole p=u-161 -> kA=u+160, kB=u+320
  int kA[6], kB[6];
#pragma unroll
  for (int j = 0; j < 6; ++j) {
    const int u = lane + 64 * j;
    int ka, kb;
    if (u == 0)        { ka = 0;       kb = ZPAD; }
    else if (u < 161)  { ka = u;       kb = u + 160; }
    else if (u < 321)  { ka = u + 160; kb = u + 320; }
    else               { ka = ZPAD;    kb = ZPAD; }
    kA[j] = ka; kB[j] = kb;
  }

  // Dq[ii][j] = D[i0+ii][kA] (plus-group value = r^t cos/sin(t*th)); 0 if inactive
  float Dq[9][6];
#pragma unroll
  for (int ii = 0; ii < 9; ++ii)
#pragma unroll
    for (int j = 0; j < 6; ++j) {
      const int u = lane + 64 * j;
      Dq[ii][j] = (u < 321) ? Dg[(i0 + ii) * KDIM + kA[j]] : 0.0f;
    }

  // ---- phase-2 D columns in registers (rows r1, r2, r3) — coalesced across lanes
  float Dc1[TT], Dc2[TT], Dc3[TT];
#pragma unroll
  for (int i = 0; i < TT; ++i) {
    Dc1[i] = Dg[i * KDIM + r1];
    Dc2[i] = Dg[i * KDIM + r2];
    Dc3[i] = has3 ? Dg[i * KDIM + r3] : 0.0f;
  }

  // ---- c0 = Linv * (D^T x_col); cm/cp thresholds
  float cm1, cp1, cm2, cp2, cm3, cp3;
  {
    float s1 = 0.f, s2 = 0.f, s3 = 0.f;
#pragma unroll
    for (int i = 0; i < TT; ++i) {
      const float xv = X[i * PP + p];
      s1 = fmaf(Dc1[i], xv, s1);
      s2 = fmaf(Dc2[i], xv, s2);
      s3 = fmaf(Dc3[i], xv, s3);
    }
    float wl1 = lamL, wl2 = lamL, wl3 = lamL;
    if (!first) {
      const float nl = Lb[2] * lamL;   // (1/||wr||) * lam * Linv
      wl1 = w[r1 * PP + p] * nl;
      wl2 = w[r2 * PP + p] * nl;
      wl3 = has3 ? (w[r3 * PP + p] * nl) : 0.0f;
    }
    const float c01 = s1 * Linv, c02 = s2 * Linv, c03 = s3 * Linv;
    cm1 = c01 - wl1; cp1 = c01 + wl1;
    cm2 = c02 - wl2; cp2 = c02 + wl2;
    cm3 = c03 - wl3; cp3 = c03 + wl3;
  }

  // ---- zero y in LDS (incl. pads, which MUST stay 0: used as zero source)
  for (int idx = tid; idx < KPAD; idx += 256) ylds[idx] = 0.0f;

  float x1 = 0.f, x2 = 0.f, x3 = 0.f;
  float y1 = 0.f, y2 = 0.f, y3 = 0.f;
  float tmom = 1.0f;

  __syncthreads();

  for (int it = 0; it < NITER; ++it) {
    // ===== phase 1: z = Linv * (D @ y), pole-paired =====
    float acc[9];
#pragma unroll
    for (int ii = 0; ii < 9; ++ii) acc[ii] = 0.f;
#pragma unroll
    for (int j = 0; j < 6; ++j) {
      const float yA = ylds[kA[j]];
      const float yB = ylds[kB[j]];
      const float a = yA + yB;       // even-t operand
      const float b = yA - yB;       // odd-t operand
      const float e0 = gOdd ? b : a; // operand for even ii (t = 9g+ii)
      const float e1 = gOdd ? a : b; // operand for odd ii
#pragma unroll
      for (int ii = 0; ii < 9; ++ii)
        acc[ii] = fmaf(Dq[ii][j], (ii & 1) ? e1 : e0, acc[ii]);
    }
    // DPP reduce (VALU pipe, no DS traffic); total lands in lane 63
    float red[9];
#pragma unroll
    for (int ii = 0; ii < 9; ++ii) red[ii] = wave_sum63(acc[ii]);
    if (lane == 63) {
#pragma unroll
      for (int ii = 0; ii < 9; ++ii) zlds[i0 + ii] = red[ii] * Linv;
    }
    __syncthreads();

    // ===== phase 2: u = y - D^T z; shrink; momentum =====
    const float tn = 0.5f * (1.0f + sqrtf(1.0f + 4.0f * tmom * tmom));
    const float mu = (tmom - 1.0f) / tn;
    tmom = tn;

    float s1 = 0.f, s2 = 0.f, s3 = 0.f;
#pragma unroll
    for (int q = 0; q < 9; ++q) {
      const float4 z4 = *reinterpret_cast<const float4*>(&zlds[4 * q]);  // broadcast
      s1 = fmaf(Dc1[4*q+0], z4.x, s1); s1 = fmaf(Dc1[4*q+1], z4.y, s1);
      s1 = fmaf(Dc1[4*q+2], z4.z, s1); s1 = fmaf(Dc1[4*q+3], z4.w, s1);
      s2 = fmaf(Dc2[4*q+0], z4.x, s2); s2 = fmaf(Dc2[4*q+1], z4.y, s2);
      s2 = fmaf(Dc2[4*q+2], z4.z, s2); s2 = fmaf(Dc2[4*q+3], z4.w, s2);
      s3 = fmaf(Dc3[4*q+0], z4.x, s3); s3 = fmaf(Dc3[4*q+1], z4.y, s3);
      s3 = fmaf(Dc3[4*q+2], z4.z, s3); s3 = fmaf(Dc3[4*q+3], z4.w, s3);
    }
    {
      float u, xn;
      u = y1 - s1; xn = fmaxf(0.f, u + cm1) + fminf(0.f, u + cp1);
      y1 = xn + mu * (xn - x1); x1 = xn;
      u = y2 - s2; xn = fmaxf(0.f, u + cm2) + fminf(0.f, u + cp2);
      y2 = xn + mu * (xn - x2); x2 = xn;
      u = y3 - s3; xn = fmaxf(0.f, u + cm3) + fminf(0.f, u + cp3);
      y3 = xn + mu * (xn - x3); x3 = xn;
      ylds[r1] = y1;
      ylds[r2] = y2;
      if (has3) ylds[r3] = y3;
    }
    __syncthreads();
  }

  xout[r1 * PP + p] = x1;
  xout[r2 * PP + p] = x2;
  if (has3) xout[r3 * PP + p] = x3;
}

// ---------------- reweighting: wr = 1/(|x|+eps), partial sums of wr^2 ----------------
__global__ void k_wr(const float* __restrict__ x, float* __restrict__ w,
                     float* __restrict__ part) {
  __shared__ float sm[256];
  int idx = blockIdx.x * 256 + threadIdx.x;
  float v = 1.0f / (fabsf(x[idx]) + EPSW);
  w[idx] = v;
  sm[threadIdx.x] = v * v;
  __syncthreads();
  for (int s = 128; s > 0; s >>= 1) {
    if (threadIdx.x < s) sm[threadIdx.x] += sm[threadIdx.x + s];
    __syncthreads();
  }
  if (threadIdx.x == 0) part[blockIdx.x] = sm[0];
}

__global__ void k_wred(const float* __restrict__ part, float* __restrict__ Lb) {
  __shared__ float sm[256];
  float s = 0.0f;
  for (int i = threadIdx.x; i < 1282; i += 256) s += part[i];
  sm[threadIdx.x] = s;
  __syncthreads();
  for (int st = 128; st > 0; st >>= 1) {
    if (threadIdx.x < st) sm[threadIdx.x] += sm[threadIdx.x + st];
    __syncthreads();
  }
  if (threadIdx.x == 0) Lb[2] = 1.0f / sqrtf(sm[0]);
}

// ---------------- host ----------------
extern "C" void kernel_launch(void* const* d_in, const int* in_sizes, int n_in,
                              void* d_out, int out_size, void* d_ws, size_t ws_size,
                              hipStream_t stream) {
  const float* x  = (const float*)d_in[0];
  const float* rr = (const float*)d_in[1];
  const float* th = (const float*)d_in[2];
  float* out = (float*)d_out;
  float* ws  = (float*)d_ws;

  size_t off = 0;
  auto alloc = [&](size_t n) {
    float* p = ws + off;
    off += (n + 63) & ~(size_t)63;
    return p;
  };
  float* D    = alloc((size_t)TT * KDIM);
  float* G    = alloc(TT * TT);
  float* Lb   = alloc(16);
  float* xa   = alloc((size_t)KDIM * PP);
  float* w    = alloc((size_t)KDIM * PP);
  float* part = alloc(1312);
  if (off * sizeof(float) > ws_size) return;  // workspace too small

  k_build_dic<<<(TT * KDIM + 255) / 256, 256, 0, stream>>>(rr, th, D, out + (size_t)KDIM * PP);
  k_G<<<(TT * TT + 255) / 256, 256, 0, stream>>>(D, G);
  k_power<<<1, 64, 0, stream>>>(G, Lb);

  for (int r = 0; r < 3; ++r) {
    float* xo = (r == 2) ? out : xa;
    k_round<<<PP, 256, 0, stream>>>(D, x, Lb, w, xo, r == 0 ? 1 : 0);
    if (r < 2) {
      k_wr<<<(KDIM * PP) / 256, 256, 0, stream>>>(xa, w, part);
      k_wred<<<1, 256, 0, stream>>>(part, Lb);
    }
  }
}